// Round 7
// baseline (376.642 us; speedup 1.0000x reference)
//
#include <hip/hip_runtime.h>
#include <math.h>

#define HEAD_DIM 256
#define N_Q 8
#define N_KV 4
#define HIDDEN 2304
#define WINDOW 1024
#define BATCH 2
#define SEQ 2048
#define BT (BATCH*SEQ)      // 4096 rows total

typedef unsigned short u16;
typedef __attribute__((ext_vector_type(8))) short bf16x8;
typedef __attribute__((ext_vector_type(4))) float f32x4;

__device__ __forceinline__ u16 f2bf(float f) {
    union { float f; unsigned u; } c; c.f = f;
    unsigned r = c.u + 0x7FFF + ((c.u >> 16) & 1);   // RNE
    return (u16)(r >> 16);
}
__device__ __forceinline__ float bf2f(u16 b) {
    union { float f; unsigned u; } c; c.u = ((unsigned)b) << 16;
    return c.f;
}

// ---------------------------------------------------------------------------
// Fused preprocessing: convert_x (blocks 0..4607) | wqkv_t (4608..6911) |
// wo_t (6912..8063).
// ---------------------------------------------------------------------------
__global__ __launch_bounds__(256) void prep_kernel(
    const float* __restrict__ x,
    const float* __restrict__ Wq, const float* __restrict__ Wk,
    const float* __restrict__ Wv, const float* __restrict__ Wo,
    u16* __restrict__ xb, u16* __restrict__ wt1, u16* __restrict__ wot)
{
    __shared__ float t[64][65];
    const int bx  = blockIdx.x;
    const int tid = threadIdx.x;

    if (bx < 4608) {
        const int i = bx * 256 + tid;
        const float4 a = ((const float4*)x)[2*i];
        const float4 b = ((const float4*)x)[2*i+1];
        u16 o[8] = { f2bf(a.x), f2bf(a.y), f2bf(a.z), f2bf(a.w),
                     f2bf(b.x), f2bf(b.y), f2bf(b.z), f2bf(b.w) };
        ((uint4*)xb)[i] = *(const uint4*)o;
        return;
    }

    if (bx < 6912) {
        const int b   = bx - 4608;
        const int j   = b / 144;
        const int rem = b % 144;
        const int d0  = (rem % 36) * 64;
        const int h0  = (rem / 36) * 64;
        const float* W = (j < 8)  ? Wq + (size_t)j*HIDDEN*HEAD_DIM
                       : (j < 12) ? Wk + (size_t)(j-8)*HIDDEN*HEAD_DIM
                                  : Wv + (size_t)(j-12)*HIDDEN*HEAD_DIM;
        {
            const int r = tid >> 4, c4 = tid & 15;
            #pragma unroll
            for (int rr = r; rr < 64; rr += 16) {
                const float4 v = *(const float4*)(W + (size_t)(d0+rr)*HEAD_DIM + h0 + c4*4);
                t[rr][c4*4+0] = v.x; t[rr][c4*4+1] = v.y;
                t[rr][c4*4+2] = v.z; t[rr][c4*4+3] = v.w;
            }
        }
        __syncthreads();
        {
            const int hh = tid >> 2;
            #pragma unroll
            for (int it = 0; it < 2; it++) {
                const int chunk = (tid & 3) + it*4;
                u16 tmp[8];
                #pragma unroll
                for (int jj = 0; jj < 8; jj++) tmp[jj] = f2bf(t[chunk*8+jj][hh]);
                *(uint4*)&wt1[(size_t)(j*256 + h0 + hh)*HIDDEN + d0 + chunk*8] = *(const uint4*)tmp;
            }
        }
        return;
    }

    {
        const int b  = bx - 6912;
        const int k0 = (b & 31) * 64;
        const int d0 = (b >> 5) * 64;
        {
            const int r = tid >> 4, c4 = tid & 15;
            #pragma unroll
            for (int rr = r; rr < 64; rr += 16) {
                const float4 v = *(const float4*)(Wo + (size_t)(k0+rr)*HIDDEN + d0 + c4*4);
                t[rr][c4*4+0] = v.x; t[rr][c4*4+1] = v.y;
                t[rr][c4*4+2] = v.z; t[rr][c4*4+3] = v.w;
            }
        }
        __syncthreads();
        {
            const int dd = tid >> 2;
            #pragma unroll
            for (int it = 0; it < 2; it++) {
                const int chunk = (tid & 3) + it*4;
                u16 tmp[8];
                #pragma unroll
                for (int jj = 0; jj < 8; jj++) tmp[jj] = f2bf(t[chunk*8+jj][dd]);
                *(uint4*)&wot[(size_t)(d0 + dd)*(N_Q*HEAD_DIM) + k0 + chunk*8] = *(const uint4*)tmp;
            }
        }
    }
}

// ---------------------------------------------------------------------------
// 256x128 bf16 GEMM, BK=32, 48 KiB LDS, 4 waves (2x2), 2 blocks/CU (R7).
//
// Mechanism change vs R2-R6 (all ~38% MfmaUtil at 1 block/CU): four schedule
// variants showed phase time = LDS + MFMA SERIAL inside one barrier domain.
// This version gets overlap from CO-RESIDENCY (m114 mechanism): two blocks
// per CU in independent barrier domains — one block's MFMA hides the other's
// LDS service. QKV grid = 16x32 = 512 = exactly 2/CU.
//
// LDS: As 256x32 x2buf (32 KB) + Bs 128x32 x2buf (16 KB) = 48 KB.
// Rows are 64 B = 4 slots of 16 B; chunk c of row r stored at slot
// c^((r>>1)&3)  (NOT ^(r&3) — that was R4's 4-way-conflict bug: parity-
// degenerate). DMA lane l (row l>>2, slot l&3) pre-fetches global chunk
// (l&3)^((l>>3)&3). Read slot = quad^((l16>>1)&3): per instr 8 lanes/16B
// slot, 8 words/bank = balanced (conflict-free).
//
// Iter = 2 K-tiles, 4 phases (buf0: ph1-2, buf1: ph3-4; mh split of M=128
// per wave). Stage tile 2t+1 -> buf1 @ ph1-2 (read ph3-4), tile 2t+2 ->
// buf0 @ ph3-4 (read next ph1-2). Drain-style WAITV(0) at ph2/ph4 ends;
// short prefetch cover is intentional — the partner block covers latency.
// ---------------------------------------------------------------------------
__device__ __forceinline__ void g128_ld_b(const u16 (&Bs)[4096], bf16x8 (&bf)[4],
                                          int wcol, int l16, int quad)
{
    const int slot = quad ^ ((l16 >> 1) & 3);
    #pragma unroll
    for (int j = 0; j < 4; j++)
        bf[j] = *(const bf16x8*)(&Bs[(wcol*64 + j*16 + l16)*32 + slot*8]);
}
template<int MH>
__device__ __forceinline__ void g128_ld_a(const u16 (&As)[8192], bf16x8 (&af)[4],
                                          int wrow, int l16, int quad)
{
    const int slot = quad ^ ((l16 >> 1) & 3);
    #pragma unroll
    for (int i = 0; i < 4; i++)
        af[i] = *(const bf16x8*)(&As[(wrow*128 + MH*64 + i*16 + l16)*32 + slot*8]);
}
template<int MH>
__device__ __forceinline__ void g128_mfma(const bf16x8 (&af)[4], const bf16x8 (&bf)[4],
                                          f32x4 (&acc)[8][4])
{
    __builtin_amdgcn_s_setprio(1);
    #pragma unroll
    for (int i = 0; i < 4; i++)
        #pragma unroll
        for (int j = 0; j < 4; j++)
            acc[MH*4+i][j] = __builtin_amdgcn_mfma_f32_16x16x32_bf16(
                                 af[i], bf[j], acc[MH*4+i][j], 0, 0, 0);
    __builtin_amdgcn_s_setprio(0);
}

// one call = 256 threads x 16 B = 64 rows of 64 B (wave w: rows R0+w*16..+15)
#define STG128(DST, SRCP, R0, KT)                                              \
    __builtin_amdgcn_global_load_lds(                                          \
        (const __attribute__((address_space(1))) unsigned int*)                \
            ((SRCP) + (size_t)(R0)*K + (size_t)(KT)*32),                       \
        (__attribute__((address_space(3))) unsigned int*)                      \
            (&DST[((R0) + wave*16)*32]),                                       \
        16, 0, 0)

#define WAITV(N) asm volatile("s_waitcnt vmcnt(" #N ")" ::: "memory")
#define BAR()    __builtin_amdgcn_s_barrier()

template<typename OutT>
__global__ __launch_bounds__(256, 2) void gemm128_kernel(
    const u16* __restrict__ A, const u16* __restrict__ Bt,
    OutT* __restrict__ C, int M, int N, int K)
{
    __shared__ __align__(16) u16 As0[8192];   // 256 rows x 32 (16 KB)
    __shared__ __align__(16) u16 As1[8192];
    __shared__ __align__(16) u16 Bs0[4096];   // 128 rows x 32 (8 KB)
    __shared__ __align__(16) u16 Bs1[4096];

    // bijective XCD swizzle (nwg % 8 == 0 for both call sites: 512, 288)
    const int nwg = gridDim.x;
    const int bid = blockIdx.x;
    const int cpx = nwg >> 3;
    const int swz = (bid & 7) * cpx + (bid >> 3);
    const int NX  = N >> 7;                // 128-wide N tiles
    const int m0  = (swz / NX) << 8;       // 256-tall M tiles
    const int n0  = (swz % NX) << 7;

    const int tid  = threadIdx.x;
    const int lane = tid & 63;
    const int wave = tid >> 6;           // 0..3
    const int wrow = wave >> 1;          // 0..1 -> rows wrow*128..+127
    const int wcol = wave & 1;           // 0..1 -> cols wcol*64..+63
    const int l16  = lane & 15;
    const int quad = lane >> 4;

    // DMA source pre-swizzle: lane l -> row l>>2, fetches chunk (l&3)^((l>>3)&3)
    const int srow   = lane >> 2;
    const int schunk = (lane & 3) ^ ((lane >> 3) & 3);
    const u16* Ag = A  + (size_t)(m0 + wave*16 + srow)*K + schunk*8;
    const u16* Bg = Bt + (size_t)(n0 + wave*16 + srow)*K + schunk*8;

    f32x4 acc[8][4];
    #pragma unroll
    for (int i = 0; i < 8; i++)
        #pragma unroll
        for (int j = 0; j < 4; j++) acc[i][j] = (f32x4){0.f,0.f,0.f,0.f};
    bf16x8 af[4], bf[4];

    const int NT = K >> 5;               // K/32 tiles (72 QKV, 64 out)

    // prologue: tile0 -> buf0 (A 4 calls + B 2 calls)
    STG128(As0, Ag,   0, 0); STG128(As0, Ag,  64, 0);
    STG128(As0, Ag, 128, 0); STG128(As0, Ag, 192, 0);
    STG128(Bs0, Bg,   0, 0); STG128(Bs0, Bg,  64, 0);
    WAITV(0);
    BAR();

    const int NI = NT >> 1;              // 2-K-tile iterations
    for (int t = 0; t < NI; ++t) {
        const int T1 = 2*t+1, T2 = 2*t+2;
        const bool nl = (t < NI-1);

        // ---- ph1: buf0 mh0; stage tile 2t+1 -> buf1 (B 2 + A 1) ----
        g128_ld_b(Bs0, bf, wcol, l16, quad);
        g128_ld_a<0>(As0, af, wrow, l16, quad);
        STG128(Bs1, Bg, 0, T1); STG128(Bs1, Bg, 64, T1);
        STG128(As1, Ag, 0, T1);
        BAR();
        g128_mfma<0>(af, bf, acc);
        BAR();

        // ---- ph2: buf0 mh1; stage As1 rest (3 calls) ----
        g128_ld_a<1>(As0, af, wrow, l16, quad);
        STG128(As1, Ag, 64, T1); STG128(As1, Ag, 128, T1); STG128(As1, Ag, 192, T1);
        BAR();
        g128_mfma<1>(af, bf, acc);
        WAITV(0);                        // tile 2t+1 fully landed before ph3
        BAR();

        // ---- ph3: buf1 mh0; stage tile 2t+2 -> buf0 (B 2 + A 1) ----
        g128_ld_b(Bs1, bf, wcol, l16, quad);
        g128_ld_a<0>(As1, af, wrow, l16, quad);
        if (nl) { STG128(Bs0, Bg, 0, T2); STG128(Bs0, Bg, 64, T2);
                  STG128(As0, Ag, 0, T2); }
        BAR();
        g128_mfma<0>(af, bf, acc);
        BAR();

        // ---- ph4: buf1 mh1; stage As0 rest (3 calls) ----
        g128_ld_a<1>(As1, af, wrow, l16, quad);
        if (nl) { STG128(As0, Ag, 64, T2); STG128(As0, Ag, 128, T2);
                  STG128(As0, Ag, 192, T2); }
        BAR();
        g128_mfma<1>(af, bf, acc);
        WAITV(0);                        // tile 2t+2 landed before next ph1
        BAR();
    }

    #pragma unroll
    for (int ii = 0; ii < 8; ii++) {
        const int rbase = m0 + wrow*128 + ii*16 + quad*4;
        #pragma unroll
        for (int j = 0; j < 4; j++) {
            const int col = n0 + wcol*64 + j*16 + l16;
            #pragma unroll
            for (int r = 0; r < 4; r++) {
                const float v = acc[ii][j][r];
                if constexpr (sizeof(OutT) == 2)
                    ((u16*)C)[(size_t)(rbase + r)*N + col] = f2bf(v);
                else
                    ((float*)C)[(size_t)(rbase + r)*N + col] = v;
            }
        }
    }
}

#undef STG128

// ---------------------------------------------------------------------------
// Fused RoPE (blocks 0..4095) + V-transpose (4096..4607).
// ---------------------------------------------------------------------------
__global__ __launch_bounds__(256) void ropevt_kernel(
    const u16* __restrict__ raw, u16* __restrict__ qb,
    u16* __restrict__ kbf, u16* __restrict__ vtt)
{
    __shared__ u16 T[32*264];
    const int bx  = blockIdx.x;
    const int tid = threadIdx.x;

    if (bx < BT) {
        const int r   = bx;
        const int pos = r & (SEQ-1);
        const u16* row = raw + (size_t)r * 4096;
        const float LOG1E4 = 9.210340371976184f;

        #pragma unroll
        for (int p = tid; p < 1024; p += 256) {   // q pairs
            const int n = p >> 7, j = p & 127;
            const float lo = bf2f(row[n*256 + j]);
            const float hi = bf2f(row[n*256 + j + 128]);
            const float inv = __expf(-LOG1E4 * (float)j * (1.0f/128.0f));
            float s, c; sincosf((float)pos * inv, &s, &c);
            qb[((size_t)r*N_Q + n)*HEAD_DIM + j]       = f2bf((lo*c - hi*s) * 0.0625f);
            qb[((size_t)r*N_Q + n)*HEAD_DIM + j + 128] = f2bf((hi*c + lo*s) * 0.0625f);
        }
        #pragma unroll
        for (int p = tid; p < 512; p += 256) {    // k pairs
            const int n = p >> 7, j = p & 127;
            const float lo = bf2f(row[2048 + n*256 + j]);
            const float hi = bf2f(row[2048 + n*256 + j + 128]);
            const float inv = __expf(-LOG1E4 * (float)j * (1.0f/128.0f));
            float s, c; sincosf((float)pos * inv, &s, &c);
            kbf[((size_t)r*N_KV + n)*HEAD_DIM + j]       = f2bf(lo*c - hi*s);
            kbf[((size_t)r*N_KV + n)*HEAD_DIM + j + 128] = f2bf(hi*c + lo*s);
        }
        return;
    }

    {
        const int blk = bx - BT;
        const int sc  = blk & 63;
        const int bk  = blk >> 6;
        const int b   = bk >> 2, kh = bk & 3;

        const u16* rrow = raw + (size_t)(b*SEQ + sc*32)*4096 + 3072 + kh*256;
        {
            const int s = tid >> 3;
            #pragma unroll
            for (int it = 0; it < 4; it++) {
                const int seg = (tid & 7) + it*8;
                *(uint4*)&T[s*264 + seg*8] = *(const uint4*)(rrow + (size_t)s*4096 + seg*8);
            }
        }
        __syncthreads();
        u16* out = vtt + (size_t)blk*8192;
        #pragma unroll
        for (int it = 0; it < 4; it++) {
            const int o = tid + it*256;
            const int h = o >> 2, ss = o & 3;
            u16 tmp[8];
            #pragma unroll
            for (int j = 0; j < 8; j++) tmp[j] = T[(ss*8 + j)*264 + h];
            *(uint4*)(out + h*32 + ((ss ^ (h & 3))*8)) = *(const uint4*)tmp;
        }
    }
}

// ---------------------------------------------------------------------------
// MFMA flash attention, fixed-max softmax (unchanged).
// ---------------------------------------------------------------------------
#define AQT 64
__global__ __launch_bounds__(256) void attn_mfma_kernel(
    const u16* __restrict__ qb, const u16* __restrict__ kb,
    const u16* __restrict__ vtt, u16* __restrict__ ao)
{
    __shared__ u16 Ks[32*264];    // K[s][d], pad 264
    __shared__ u16 Vs[256*32];    // V^T[h][s-chunks swizzled], unpadded (DMA)
    __shared__ u16 Ps[64*40];     // P[t][s], pad 40
    __shared__ float lsum[64];

    const int qh = blockIdx.y;
    const int kh = qh >> 1;
    const int bx = ((blockIdx.y >> 2) & 1) ? (gridDim.x - 1 - (int)blockIdx.x)
                                           : (int)blockIdx.x;
    const int t0 = bx * AQT;
    const int b  = t0 >> 11;
    const int tb = t0 & (SEQ-1);
    const int tid  = threadIdx.x;
    const int wave = tid >> 6;
    const int lane = tid & 63;
    const int l16  = lane & 15;
    const int quad = lane >> 4;

    bf16x8 qf[8];
    {
        const u16* qrow = qb + ((size_t)(t0 + wave*16 + l16)*N_Q + qh)*HEAD_DIM + quad*8;
        #pragma unroll
        for (int c = 0; c < 8; c++) qf[c] = *(const bf16x8*)(qrow + c*32);
    }

    f32x4 o[4][4];
    #pragma unroll
    for (int i = 0; i < 4; i++)
        #pragma unroll
        for (int j = 0; j < 4; j++) o[i][j] = (f32x4){0.f,0.f,0.f,0.f};
    float lpart[4] = {0.f, 0.f, 0.f, 0.f};

    int s_begin = tb - (WINDOW-1); if (s_begin < 0) s_begin = 0;
    const int st0 = s_begin & ~31;

    const u16* kbase = kb  + ((size_t)(b*SEQ)*N_KV + kh)*HEAD_DIM;
    const u16* vbase = vtt + ((size_t)(b*N_KV + kh)*SEQ)*HEAD_DIM;

    for (int st = st0; st < tb + AQT; st += 32) {
        __syncthreads();
        {   // V tile via DMA: 16 KB contiguous, 4 calls/wave
            const u16* vtile = vbase + (size_t)st*HEAD_DIM;
            #pragma unroll
            for (int c = 0; c < 4; c++) {
                const int off = wave*2048 + c*512;
                __builtin_amdgcn_global_load_lds(
                    (const __attribute__((address_space(1))) unsigned int*)(vtile + off + lane*8),
                    (__attribute__((address_space(3))) unsigned int*)&Vs[off],
                    16, 0, 0);
            }
            // K tile manual (padded 264)
            const int s = tid >> 3;
            const u16* krow = kbase + (size_t)(st + s)*(N_KV*HEAD_DIM);
            #pragma unroll
            for (int it = 0; it < 4; it++) {
                const int seg = (tid & 7) + it*8;
                *(uint4*)&Ks[s*264 + seg*8] = *(const uint4*)(krow + seg*8);
            }
        }
        __syncthreads();

        // QK^T: wave rows wave*16..+15, S[16][32]
        f32x4 sc[2];
        #pragma unroll
        for (int sf = 0; sf < 2; sf++) {
            f32x4 a = (f32x4){0.f,0.f,0.f,0.f};
            const u16* kr = &Ks[(sf*16 + l16)*264 + quad*8];
            #pragma unroll
            for (int c = 0; c < 8; c++)
                a = __builtin_amdgcn_mfma_f32_16x16x32_bf16(
                        qf[c], *(const bf16x8*)(kr + c*32), a, 0, 0, 0);
            sc[sf] = a;
        }

        // fused soft-cap + fixed-max softmax, write P
        #pragma unroll
        for (int sf = 0; sf < 2; sf++) {
            const int sg = st + sf*16 + l16;
            #pragma unroll
            for (int r = 0; r < 4; r++) {
                const int tg = tb + wave*16 + quad*4 + r;
                const float e1 = __expf(sc[sf][r] * 0.04f);       // e^{S/25}
                float p = __expf(-100.0f / (e1 + 1.0f));          // exp(cap-50)
                const bool ok = (sg <= tg) && (tg - sg < WINDOW);
                p = ok ? p : 0.0f;
                lpart[r] += p;
                Ps[(wave*16 + quad*4 + r)*40 + sf*16 + l16] = f2bf(p);
            }
        }
        __syncthreads();   // Ps complete (all 64 rows)

        // PV: wave owns h-cols wave*64..+63, all 64 rows
        bf16x8 ap[4];
        #pragma unroll
        for (int i = 0; i < 4; i++)
            ap[i] = *(const bf16x8*)&Ps[(i*16 + l16)*40 + quad*8];
        #pragma unroll
        for (int j = 0; j < 4; j++) {
            const int hr = wave*64 + j*16 + l16;
            const bf16x8 bv = *(const bf16x8*)&Vs[hr*32 + ((quad ^ (l16 & 3))*8)];
            #pragma unroll
            for (int i = 0; i < 4; i++)
                o[i][j] = __builtin_amdgcn_mfma_f32_16x16x32_bf16(ap[i], bv, o[i][j], 0, 0, 0);
        }
    }

    // row sums -> LDS (QK rows are wave-owned)
    #pragma unroll
    for (int r = 0; r < 4; r++) {
        float s = lpart[r];
        #pragma unroll
        for (int sh = 1; sh <= 8; sh <<= 1) s += __shfl_xor(s, sh, 64);
        if (l16 == 0) lsum[wave*16 + quad*4 + r] = s;
    }
    __syncthreads();

    #pragma unroll
    for (int i = 0; i < 4; i++) {
        #pragma unroll
        for (int r = 0; r < 4; r++) {
            const int rl  = i*16 + quad*4 + r;
            const float inv = 1.0f / (lsum[rl] + 1e-30f);
            u16* arow = ao + ((size_t)(t0 + rl)*N_Q + qh)*HEAD_DIM + wave*64 + l16;
            #pragma unroll
            for (int j = 0; j < 4; j++)
                arow[j*16] = f2bf(o[i][j][r] * inv);
        }
    }
}

// ---------------------------------------------------------------------------
extern "C" void kernel_launch(void* const* d_in, const int* in_sizes, int n_in,
                              void* d_out, int out_size, void* d_ws, size_t ws_size,
                              hipStream_t stream)
{
    const float* x  = (const float*)d_in[0];
    // d_in[1] = attention_mask: exactly causal(tril) -> not needed.
    const float* Wq = (const float*)d_in[2];
    const float* Wk = (const float*)d_in[3];
    const float* Wv = (const float*)d_in[4];
    const float* Wo = (const float*)d_in[5];
    float* out = (float*)d_out;

    char* w = (char*)d_ws;
    u16* qbuf = (u16*)(w);                     // 16,777,216
    u16* kbuf = (u16*)(w +  16777216ull);      //  8,388,608
    u16* vtt  = (u16*)(w +  25165824ull);      //  8,388,608
    u16* aob  = (u16*)(w +  33554432ull);      // 16,777,216
    u16* xb   = (u16*)(w +  50331648ull);      // 18,874,368
    u16* wt1  = (u16*)(w +  69206016ull);      // 18,874,368
    u16* wot  = (u16*)(w +  88080384ull);      //  9,437,184
    u16* raw  = (u16*)(w +  97517568ull);      // 33,554,432 (end ~131 MB)

    // 1) fused preprocessing
    prep_kernel<<<8064, 256, 0, stream>>>(x, Wq, Wk, Wv, Wo, xb, wt1, wot);

    // 2) QKV GEMM: 256x128 tile, 512 blocks = 2 co-resident blocks/CU.
    gemm128_kernel<u16><<<(BT/256)*(4096/128), 256, 0, stream>>>(
        xb, wt1, raw, BT, 4096, HIDDEN);

    // 3) fused RoPE + V-transpose
    ropevt_kernel<<<BT + BATCH*N_KV*64, 256, 0, stream>>>(raw, qbuf, kbuf, vtt);

    // 4) attention
    attn_mfma_kernel<<<dim3(BT/AQT, N_Q), 256, 0, stream>>>(qbuf, kbuf, vtt, aob);

    // 5) output GEMM: 16x18 = 288 blocks (%8==0, bijective swizzle holds).
    gemm128_kernel<float><<<(BT/256)*(HIDDEN/128), 256, 0, stream>>>(
        aob, wot, out, BT, HIDDEN, N_Q*HEAD_DIM);
}